// Round 6
// baseline (168.893 us; speedup 1.0000x reference)
//
#include <hip/hip_runtime.h>
#include <hip/hip_bf16.h>
#include <math.h>

// Problem constants
constexpr int BB = 8;
constexpr int CC = 256;
constexpr int TT = 2048;
constexpr int RR = 32;      // reduced dim

// attn
constexpr int ATILE = 32;   // t rows per attn block
constexpr int PS = 72;      // Ps stride (bf16), 144B rows

// proj
constexpr int PT  = 32;     // t-tile
constexpr int XS32 = 33;    // fp32 [c][t] stride
constexpr int XSB  = 264;   // bf16 [t][c] stride (528B rows)

constexpr float FIXEDM = 24.0f;  // fixed softmax shift; scores ~N(0,5.7)

typedef short short8 __attribute__((ext_vector_type(8)));
typedef float f32x4 __attribute__((ext_vector_type(4)));
typedef unsigned short us4 __attribute__((ext_vector_type(4)));

static __device__ __forceinline__ unsigned short f2bf(float f) {
    __hip_bfloat16 h = __float2bfloat16(f);
    return *reinterpret_cast<unsigned short*>(&h);
}

// ---------------------------------------------------------------------------
// One-shot W cast fp32 -> bf16.
// ---------------------------------------------------------------------------
__global__ __launch_bounds__(256) void wcast_kernel(
    const float* __restrict__ Wq, const float* __restrict__ Wk,
    const float* __restrict__ Wv,
    unsigned short* __restrict__ wqb, unsigned short* __restrict__ wkb,
    unsigned short* __restrict__ wvb)
{
    int g = blockIdx.x * 256 + threadIdx.x;   // float4 index, 20480 total
    const float* src; unsigned short* dst; int i4;
    if (g < 2048)       { src = Wq; dst = wqb; i4 = g; }
    else if (g < 4096)  { src = Wk; dst = wkb; i4 = g - 2048; }
    else                { src = Wv; dst = wvb; i4 = g - 4096; }
    float4 v = *(const float4*)(src + i4 * 4);
    us4 p;
    p[0] = f2bf(v.x); p[1] = f2bf(v.y); p[2] = f2bf(v.z); p[3] = f2bf(v.w);
    *(us4*)(dst + i4 * 4) = p;
}

// ---------------------------------------------------------------------------
// MFMA projection (unchanged from R5). 512 blocks, 2-3 blocks/CU.
// ---------------------------------------------------------------------------
__global__ __launch_bounds__(256, 2) void proj_kernel(
    const float* __restrict__ x,
    const unsigned short* __restrict__ wqb, const float* __restrict__ bq,
    const unsigned short* __restrict__ wkb, const float* __restrict__ bk,
    const unsigned short* __restrict__ wvb, const float* __restrict__ bv,
    unsigned short* __restrict__ qws, unsigned short* __restrict__ kws,
    unsigned short* __restrict__ vws)
{
    __shared__ float xs32[CC * XS32];            // [c][t] 33.8 KB
    __shared__ unsigned short xsb[PT * XSB];     // [t][c] 16.9 KB

    const int tid = threadIdx.x;
    const int t0  = blockIdx.x * PT;
    const int b   = blockIdx.y;
    const float* xb = x + (size_t)b * CC * TT;

    #pragma unroll
    for (int m = 0; m < 8; ++m) {
        int lin = m * 256 + tid;     // float4 index
        int c   = lin >> 3;
        int t4  = lin & 7;
        float4 v = *(const float4*)(xb + (size_t)c * TT + t0 + t4 * 4);
        float* d = &xs32[c * XS32 + t4 * 4];
        d[0] = v.x; d[1] = v.y; d[2] = v.z; d[3] = v.w;
    }
    __syncthreads();
    {
        int c = tid;
        #pragma unroll
        for (int t = 0; t < PT; ++t)
            xsb[t * XSB + c] = f2bf(xs32[c * XS32 + t]);
    }
    __syncthreads();

    const int lane = tid & 63;
    const int w    = __builtin_amdgcn_readfirstlane(tid >> 6);
    const int l15  = lane & 15;
    const int quad = lane >> 4;

    const unsigned short* Wt[5]; const float* bt[5]; int rl[5]; int seg[5];
    #pragma unroll
    for (int i = 0; i < 5; ++i) {
        int mt = w * 5 + i;
        if (mt < 2)      { Wt[i] = wqb; bt[i] = bq; rl[i] = mt * 16;       seg[i] = 0; }
        else if (mt < 4) { Wt[i] = wkb; bt[i] = bk; rl[i] = (mt - 2) * 16; seg[i] = 1; }
        else             { Wt[i] = wvb; bt[i] = bv; rl[i] = (mt - 4) * 16; seg[i] = 2; }
    }

    f32x4 acc[5][2];
    #pragma unroll
    for (int i = 0; i < 5; ++i) {
        float4 bb = *(const float4*)(bt[i] + rl[i] + quad * 4);
        #pragma unroll
        for (int nt = 0; nt < 2; ++nt)
            acc[i][nt] = (f32x4){bb.x, bb.y, bb.z, bb.w};
    }

    #pragma unroll
    for (int ks = 0; ks < 8; ++ks) {
        short8 bfr[2];
        #pragma unroll
        for (int nt = 0; nt < 2; ++nt)
            bfr[nt] = *(const short8*)(&xsb[(nt * 16 + l15) * XSB + ks * 32 + quad * 8]);
        #pragma unroll
        for (int i = 0; i < 5; ++i) {
            short8 af = *(const short8*)(Wt[i] + (size_t)(rl[i] + l15) * CC + ks * 32 + quad * 8);
            #pragma unroll
            for (int nt = 0; nt < 2; ++nt)
                acc[i][nt] = __builtin_amdgcn_mfma_f32_16x16x32_bf16(
                    af, bfr[nt], acc[i][nt], 0, 0, 0);
        }
    }

    #pragma unroll
    for (int i = 0; i < 5; ++i) {
        if (seg[i] < 2) {
            unsigned short* outt = (seg[i] == 0 ? qws : kws) + (size_t)b * TT * RR;
            #pragma unroll
            for (int nt = 0; nt < 2; ++nt) {
                int t = t0 + nt * 16 + l15;
                us4 pk;
                pk[0] = f2bf(acc[i][nt][0]); pk[1] = f2bf(acc[i][nt][1]);
                pk[2] = f2bf(acc[i][nt][2]); pk[3] = f2bf(acc[i][nt][3]);
                *(us4*)(outt + (size_t)t * RR + rl[i] + quad * 4) = pk;
            }
        } else {
            unsigned short* vt = vws + (size_t)b * CC * TT;
            #pragma unroll
            for (int nt = 0; nt < 2; ++nt)
                #pragma unroll
                for (int r = 0; r < 4; ++r)
                    vt[(size_t)(rl[i] + quad * 4 + r) * TT + t0 + nt * 16 + l15] =
                        f2bf(acc[i][nt][r]);
        }
    }
}

// ---------------------------------------------------------------------------
// MFMA flash attention v6: fixed-max softmax, 4 waves, t-tile 32, grid 512.
// ONE barrier per 64-s chunk (double-buffered Ps); K/V B-frags direct from
// global (L2, XCD-local), prefetched right AFTER the barrier and consumed a
// full chunk later -> no outstanding globals at any barrier (no drain stall).
// S-tiles split across waves: wave w -> (mt = w&1, s-half = w>>1).
// PV: wave w owns c-slab [w*64, +64), acc[2 mt][4 nt].
// ---------------------------------------------------------------------------
__global__ __launch_bounds__(256, 3) void attn_kernel(
    const float* __restrict__ x,
    const unsigned short* __restrict__ qws, const unsigned short* __restrict__ kws,
    const unsigned short* __restrict__ vws, const float* __restrict__ gamma_p,
    float* __restrict__ out)
{
    __shared__ unsigned short Ps[2][ATILE * PS];   // 9.2 KB
    __shared__ float lsum[2][ATILE];

    const int tid  = threadIdx.x;
    const int b    = blockIdx.x;             // id%8 = b -> XCD-local K/V in L2
    const int t0   = blockIdx.y * ATILE;
    const int lane = tid & 63;
    const int w    = __builtin_amdgcn_readfirstlane(tid >> 6);   // 0..3
    const int mt_w = w & 1;                  // S row-tile
    const int sh_w = w >> 1;                 // S s-half
    const int l15  = lane & 15;
    const int quad = lane >> 4;

    const unsigned short* qb = qws + (size_t)b * TT * RR;
    const unsigned short* kb = kws + (size_t)b * TT * RR;
    const unsigned short* vb = vws + (size_t)b * CC * TT;

    // Q A-frag for the wave's S rows
    short8 qfrag = *(const short8*)(qb + (size_t)(t0 + mt_w * 16 + l15) * RR + quad * 8);

    // V B-frag base: c = w*64 + nt*16 + l15, s = s0 + ks*32 + quad*8
    const unsigned short* vbase = vb + (size_t)(w * 64 + l15) * TT + quad * 8;
    // K B-frag base: s-row = s0 + (sh_w*2+i)*16 + l15
    const unsigned short* kbase = kb + (size_t)(sh_w * 32 + l15) * RR + quad * 8;

    float rs[4];
    #pragma unroll
    for (int r = 0; r < 4; ++r) rs[r] = 0.0f;

    f32x4 acc[2][4];
    #pragma unroll
    for (int mt = 0; mt < 2; ++mt)
        #pragma unroll
        for (int nt = 0; nt < 4; ++nt)
            acc[mt][nt] = (f32x4){0.f, 0.f, 0.f, 0.f};

    const f32x4 zz = (f32x4){0.f, 0.f, 0.f, 0.f};

    short8 kA[2], kB[2], vA[8], vB[8];

    // prologue: prefetch chunk 0 into the A set
    #pragma unroll
    for (int i = 0; i < 2; ++i)
        kA[i] = *(const short8*)(kbase + (size_t)(i * 16) * RR);
    #pragma unroll
    for (int ks = 0; ks < 2; ++ks)
        #pragma unroll
        for (int nt = 0; nt < 4; ++nt)
            vA[ks * 4 + nt] = *(const short8*)(vbase + (size_t)(nt * 16) * TT + ks * 32);

    auto do_chunk = [&](int j, short8* kc, short8* vc, short8* kn, short8* vn) {
        // ---- S = Q K^T (2 tiles) ----
        f32x4 st[2];
        #pragma unroll
        for (int i = 0; i < 2; ++i)
            st[i] = __builtin_amdgcn_mfma_f32_16x16x32_bf16(qfrag, kc[i], zz, 0, 0, 0);

        // ---- P = exp(S-M), row-sum partials, Ps[par] ----
        const int par  = j & 1;
        const int prow = mt_w * 16 + quad * 4;
        const int scol = sh_w * 32;
        #pragma unroll
        for (int i = 0; i < 2; ++i) {
            #pragma unroll
            for (int r = 0; r < 4; ++r) {
                float e = __expf(st[i][r] - FIXEDM);
                rs[r] += e;
                Ps[par][(prow + r) * PS + scol + i * 16 + l15] = f2bf(e);
            }
        }
        __syncthreads();   // publishes Ps[par]; no globals outstanding here

        // ---- prefetch chunk j+1 (consumed next chunk, after next barrier) ----
        const int s1 = (j + 1 < 32) ? (j + 1) * 64 : 0;   // clamp: harmless
        #pragma unroll
        for (int i = 0; i < 2; ++i)
            kn[i] = *(const short8*)(kbase + (size_t)(i * 16) * RR + (size_t)s1 * RR);
        #pragma unroll
        for (int ks = 0; ks < 2; ++ks)
            #pragma unroll
            for (int nt = 0; nt < 4; ++nt)
                vn[ks * 4 + nt] = *(const short8*)(vbase + (size_t)(nt * 16) * TT + s1 + ks * 32);

        // ---- O += P V ----
        #pragma unroll
        for (int ks = 0; ks < 2; ++ks) {
            short8 pa[2];
            #pragma unroll
            for (int mt = 0; mt < 2; ++mt)
                pa[mt] = *(const short8*)(&Ps[par][(mt * 16 + l15) * PS + ks * 32 + quad * 8]);
            #pragma unroll
            for (int mt = 0; mt < 2; ++mt)
                #pragma unroll
                for (int nt = 0; nt < 4; ++nt)
                    acc[mt][nt] = __builtin_amdgcn_mfma_f32_16x16x32_bf16(
                        pa[mt], vc[ks * 4 + nt], acc[mt][nt], 0, 0, 0);
        }
    };

    #pragma unroll 1
    for (int j = 0; j < 32; j += 2) {
        do_chunk(j,     kA, vA, kB, vB);
        do_chunk(j + 1, kB, vB, kA, vA);
    }

    // K-frag s0 offset fix: kbase already includes l15; per-chunk s offset was
    // folded via (s1*RR). (chunk j's kc was prefetched with s = j*64.)

    // ---- l: reduce over the 16 s-columns, publish per (s-half, row) ----
    #pragma unroll
    for (int mask = 1; mask < 16; mask <<= 1)
        #pragma unroll
        for (int r = 0; r < 4; ++r)
            rs[r] += __shfl_xor(rs[r], mask, 64);
    if (l15 == 0) {
        #pragma unroll
        for (int r = 0; r < 4; ++r)
            lsum[sh_w][mt_w * 16 + quad * 4 + r] = rs[r];
    }
    __syncthreads();

    // ---- epilogue: out = x + gamma * O / l ----
    const float gam = gamma_p[0];
    const float* xb = x + (size_t)b * CC * TT;
    float* ob = out + (size_t)b * CC * TT;

    #pragma unroll
    for (int mt = 0; mt < 2; ++mt) {
        f32x4 l0 = *(const f32x4*)(&lsum[0][mt * 16 + quad * 4]);
        f32x4 l1 = *(const f32x4*)(&lsum[1][mt * 16 + quad * 4]);
        float li[4];
        #pragma unroll
        for (int r = 0; r < 4; ++r) li[r] = 1.0f / (l0[r] + l1[r]);
        #pragma unroll
        for (int nt = 0; nt < 4; ++nt) {
            int c = w * 64 + nt * 16 + l15;
            size_t gidx = (size_t)c * TT + t0 + mt * 16 + quad * 4;
            float4 xv = *(const float4*)(xb + gidx);
            float4 ov;
            ov.x = xv.x + gam * acc[mt][nt][0] * li[0];
            ov.y = xv.y + gam * acc[mt][nt][1] * li[1];
            ov.z = xv.z + gam * acc[mt][nt][2] * li[2];
            ov.w = xv.w + gam * acc[mt][nt][3] * li[3];
            *(float4*)(ob + gidx) = ov;
        }
    }
}

// ---------------------------------------------------------------------------
extern "C" void kernel_launch(void* const* d_in, const int* in_sizes, int n_in,
                              void* d_out, int out_size, void* d_ws, size_t ws_size,
                              hipStream_t stream)
{
    const float* x     = (const float*)d_in[0];
    const float* Wq    = (const float*)d_in[1];
    const float* bq    = (const float*)d_in[2];
    const float* Wk    = (const float*)d_in[3];
    const float* bk    = (const float*)d_in[4];
    const float* Wv    = (const float*)d_in[5];
    const float* bv    = (const float*)d_in[6];
    const float* gamma = (const float*)d_in[7];
    float* out = (float*)d_out;

    unsigned short* qws = (unsigned short*)d_ws;            // [B][T][R] bf16
    unsigned short* kws = qws + (size_t)BB * TT * RR;       // [B][T][R] bf16
    unsigned short* vws = kws + (size_t)BB * TT * RR;       // [B][C][T] bf16
    unsigned short* wqb = vws + (size_t)BB * CC * TT;       // [R][C] bf16
    unsigned short* wkb = wqb + (size_t)RR * CC;
    unsigned short* wvb = wkb + (size_t)RR * CC;            // [C][C] bf16

    wcast_kernel<<<80, 256, 0, stream>>>(Wq, Wk, Wv, wqb, wkb, wvb);

    dim3 pgrid(TT / PT, BB);
    proj_kernel<<<pgrid, 256, 0, stream>>>(x, wqb, bq, wkb, bk, wvb, bv, qws, kws, vws);

    dim3 agrid(BB, TT / ATILE);
    attn_kernel<<<agrid, 256, 0, stream>>>(x, qws, kws, vws, gamma, out);
}

// Round 7
// 137.714 us; speedup vs baseline: 1.2264x; 1.2264x over previous
//
#include <hip/hip_runtime.h>
#include <hip/hip_bf16.h>
#include <math.h>

// Problem constants
constexpr int BB = 8;
constexpr int CC = 256;
constexpr int TT = 2048;
constexpr int RR = 32;      // reduced dim

// attn
constexpr int ATILE = 32;   // t rows per attn block
constexpr int PS = 72;      // Ps stride (bf16), 144B rows (bank-uniform b128 reads)
// Vs: swizzled, stride 64 bf16 = 128B rows. Element (c,s): 16B slot within row
// = (s>>3) ^ (c&7). Staging writes and frag reads both hit the 2-per-bank
// wave64 minimum (conflict-free).

// proj
constexpr int PT  = 32;     // t-tile
constexpr int XS32 = 33;    // fp32 [c][t] stride
constexpr int XSB  = 264;   // bf16 [t][c] stride (528B rows)

constexpr float FIXEDM = 24.0f;  // fixed softmax shift; scores ~N(0,5.7)

typedef short short8 __attribute__((ext_vector_type(8)));
typedef float f32x4 __attribute__((ext_vector_type(4)));
typedef unsigned short us4 __attribute__((ext_vector_type(4)));

static __device__ __forceinline__ unsigned short f2bf(float f) {
    __hip_bfloat16 h = __float2bfloat16(f);
    return *reinterpret_cast<unsigned short*>(&h);
}

// ---------------------------------------------------------------------------
// One-shot W cast fp32 -> bf16.
// ---------------------------------------------------------------------------
__global__ __launch_bounds__(256) void wcast_kernel(
    const float* __restrict__ Wq, const float* __restrict__ Wk,
    const float* __restrict__ Wv,
    unsigned short* __restrict__ wqb, unsigned short* __restrict__ wkb,
    unsigned short* __restrict__ wvb)
{
    int g = blockIdx.x * 256 + threadIdx.x;   // float4 index, 20480 total
    const float* src; unsigned short* dst; int i4;
    if (g < 2048)       { src = Wq; dst = wqb; i4 = g; }
    else if (g < 4096)  { src = Wk; dst = wkb; i4 = g - 2048; }
    else                { src = Wv; dst = wvb; i4 = g - 4096; }
    float4 v = *(const float4*)(src + i4 * 4);
    us4 p;
    p[0] = f2bf(v.x); p[1] = f2bf(v.y); p[2] = f2bf(v.z); p[3] = f2bf(v.w);
    *(us4*)(dst + i4 * 4) = p;
}

// ---------------------------------------------------------------------------
// MFMA projection (unchanged from R6: ~18 us). 512 blocks.
// ---------------------------------------------------------------------------
__global__ __launch_bounds__(256, 2) void proj_kernel(
    const float* __restrict__ x,
    const unsigned short* __restrict__ wqb, const float* __restrict__ bq,
    const unsigned short* __restrict__ wkb, const float* __restrict__ bk,
    const unsigned short* __restrict__ wvb, const float* __restrict__ bv,
    unsigned short* __restrict__ qws, unsigned short* __restrict__ kws,
    unsigned short* __restrict__ vws)
{
    __shared__ float xs32[CC * XS32];            // [c][t] 33.8 KB
    __shared__ unsigned short xsb[PT * XSB];     // [t][c] 16.9 KB

    const int tid = threadIdx.x;
    const int t0  = blockIdx.x * PT;
    const int b   = blockIdx.y;
    const float* xb = x + (size_t)b * CC * TT;

    #pragma unroll
    for (int m = 0; m < 8; ++m) {
        int lin = m * 256 + tid;     // float4 index
        int c   = lin >> 3;
        int t4  = lin & 7;
        float4 v = *(const float4*)(xb + (size_t)c * TT + t0 + t4 * 4);
        float* d = &xs32[c * XS32 + t4 * 4];
        d[0] = v.x; d[1] = v.y; d[2] = v.z; d[3] = v.w;
    }
    __syncthreads();
    {
        int c = tid;
        #pragma unroll
        for (int t = 0; t < PT; ++t)
            xsb[t * XSB + c] = f2bf(xs32[c * XS32 + t]);
    }
    __syncthreads();

    const int lane = tid & 63;
    const int w    = __builtin_amdgcn_readfirstlane(tid >> 6);
    const int l15  = lane & 15;
    const int quad = lane >> 4;

    const unsigned short* Wt[5]; const float* bt[5]; int rl[5]; int seg[5];
    #pragma unroll
    for (int i = 0; i < 5; ++i) {
        int mt = w * 5 + i;
        if (mt < 2)      { Wt[i] = wqb; bt[i] = bq; rl[i] = mt * 16;       seg[i] = 0; }
        else if (mt < 4) { Wt[i] = wkb; bt[i] = bk; rl[i] = (mt - 2) * 16; seg[i] = 1; }
        else             { Wt[i] = wvb; bt[i] = bv; rl[i] = (mt - 4) * 16; seg[i] = 2; }
    }

    f32x4 acc[5][2];
    #pragma unroll
    for (int i = 0; i < 5; ++i) {
        float4 bb = *(const float4*)(bt[i] + rl[i] + quad * 4);
        #pragma unroll
        for (int nt = 0; nt < 2; ++nt)
            acc[i][nt] = (f32x4){bb.x, bb.y, bb.z, bb.w};
    }

    #pragma unroll
    for (int ks = 0; ks < 8; ++ks) {
        short8 bfr[2];
        #pragma unroll
        for (int nt = 0; nt < 2; ++nt)
            bfr[nt] = *(const short8*)(&xsb[(nt * 16 + l15) * XSB + ks * 32 + quad * 8]);
        #pragma unroll
        for (int i = 0; i < 5; ++i) {
            short8 af = *(const short8*)(Wt[i] + (size_t)(rl[i] + l15) * CC + ks * 32 + quad * 8);
            #pragma unroll
            for (int nt = 0; nt < 2; ++nt)
                acc[i][nt] = __builtin_amdgcn_mfma_f32_16x16x32_bf16(
                    af, bfr[nt], acc[i][nt], 0, 0, 0);
        }
    }

    #pragma unroll
    for (int i = 0; i < 5; ++i) {
        if (seg[i] < 2) {
            unsigned short* outt = (seg[i] == 0 ? qws : kws) + (size_t)b * TT * RR;
            #pragma unroll
            for (int nt = 0; nt < 2; ++nt) {
                int t = t0 + nt * 16 + l15;
                us4 pk;
                pk[0] = f2bf(acc[i][nt][0]); pk[1] = f2bf(acc[i][nt][1]);
                pk[2] = f2bf(acc[i][nt][2]); pk[3] = f2bf(acc[i][nt][3]);
                *(us4*)(outt + (size_t)t * RR + rl[i] + quad * 4) = pk;
            }
        } else {
            unsigned short* vt = vws + (size_t)b * CC * TT;
            #pragma unroll
            for (int nt = 0; nt < 2; ++nt)
                #pragma unroll
                for (int r = 0; r < 4; ++r)
                    vt[(size_t)(rl[i] + quad * 4 + r) * TT + t0 + nt * 16 + l15] =
                        f2bf(acc[i][nt][r]);
        }
    }
}

// ---------------------------------------------------------------------------
// MFMA flash attention v7: fixed-max softmax, 4 waves, t-tile 32, grid 512,
// 2 blocks/CU. ONE barrier per 64-s chunk:
//   - Vs double-buffered (swizzled, 2x32 KB) via short-live-range staging
//     (global short8 -> regs -> ds_write after the barrier)
//   - Ps double-buffered (2x4.6 KB)
//   - K prefetched one chunk ahead in 2 short8 regs (contiguous 1KB loads)
// Barrier j publishes Ps[j&1]; by reaching it, all waves finished reading
// Vs[(j+1)&1] (prev PV), so post-barrier ds_writes into it are safe. The
// vmcnt(0) drain at barrier j waits on loads issued at the top of iter j
// (~S+exp phase earlier) -> mostly landed.
// Wave w: S tiles (mt=w&1, s-half=w>>1); PV c-slab [w*64, +64), acc[2][4].
// ---------------------------------------------------------------------------
__global__ __launch_bounds__(256, 2) void attn_kernel(
    const float* __restrict__ x,
    const unsigned short* __restrict__ qws, const unsigned short* __restrict__ kws,
    const unsigned short* __restrict__ vws, const float* __restrict__ gamma_p,
    float* __restrict__ out)
{
    __shared__ unsigned short Vs[2][CC * 64];      // swizzled [c][slot], 64 KB
    __shared__ unsigned short Ps[2][ATILE * PS];   // 9.2 KB
    __shared__ float lsum[2][ATILE];

    const int tid  = threadIdx.x;
    const int b    = blockIdx.x;             // linear%8 = b -> XCD-local K/V L2
    const int t0   = blockIdx.y * ATILE;
    const int lane = tid & 63;
    const int w    = __builtin_amdgcn_readfirstlane(tid >> 6);   // 0..3
    const int mt_w = w & 1;                  // S row-tile
    const int sh_w = w >> 1;                 // S s-half
    const int l15  = lane & 15;
    const int quad = lane >> 4;

    const unsigned short* qb = qws + (size_t)b * TT * RR;
    const unsigned short* kb = kws + (size_t)b * TT * RR;
    const unsigned short* vb = vws + (size_t)b * CC * TT;

    // Q A-frag for the wave's S rows
    short8 qfrag = *(const short8*)(qb + (size_t)(t0 + mt_w * 16 + l15) * RR + quad * 8);

    // V staging identity: inst m covers 16B slots o16 = m*256 + tid.
    // c = m*32 + (tid>>3), slot = tid&7, s-group = slot ^ (c&7).
    const int crow = tid >> 3;                       // 0..31
    const int sgx  = (tid & 7) ^ (crow & 7);         // s-group for this thread
    const unsigned short* vstg = vb + (size_t)crow * TT + sgx * 8;

    // K B-frag base: s-row = s0 + sh_w*32 + i*16 + l15
    const unsigned short* kbase = kb + (size_t)(sh_w * 32 + l15) * RR + quad * 8;

    float rs[4];
    #pragma unroll
    for (int r = 0; r < 4; ++r) rs[r] = 0.0f;

    f32x4 acc[2][4];
    #pragma unroll
    for (int mt = 0; mt < 2; ++mt)
        #pragma unroll
        for (int nt = 0; nt < 4; ++nt)
            acc[mt][nt] = (f32x4){0.f, 0.f, 0.f, 0.f};

    const f32x4 zz = (f32x4){0.f, 0.f, 0.f, 0.f};

    short8 vreg[8], kcur[2], kn[2];

    // ---- prologue: chunk 0 -> Vs[0], K(0) -> kcur ----
    #pragma unroll
    for (int m = 0; m < 8; ++m)
        vreg[m] = *(const short8*)(vstg + (size_t)(m * 32) * TT);
    #pragma unroll
    for (int i = 0; i < 2; ++i)
        kcur[i] = *(const short8*)(kbase + (size_t)(i * 16) * RR);
    #pragma unroll
    for (int m = 0; m < 8; ++m)
        *(short8*)(&Vs[0][(m * 256 + tid) * 8]) = vreg[m];

    #pragma unroll 2
    for (int j = 0; j < 32; ++j) {
        // ---- issue next chunk's staging loads (wrap at 31: harmless) ----
        const int s1 = ((j + 1) & 31) * 64;
        #pragma unroll
        for (int m = 0; m < 8; ++m)
            vreg[m] = *(const short8*)(vstg + (size_t)(m * 32) * TT + s1);
        #pragma unroll
        for (int i = 0; i < 2; ++i)
            kn[i] = *(const short8*)(kbase + (size_t)(s1 + i * 16) * RR);

        // ---- S = Q K^T (2 tiles, K from regs) ----
        f32x4 st[2];
        #pragma unroll
        for (int i = 0; i < 2; ++i)
            st[i] = __builtin_amdgcn_mfma_f32_16x16x32_bf16(qfrag, kcur[i], zz, 0, 0, 0);

        // ---- P = exp(S-M), row-sum partials, Ps[j&1] ----
        const int prow = mt_w * 16 + quad * 4;
        const int scol = sh_w * 32;
        #pragma unroll
        for (int i = 0; i < 2; ++i) {
            #pragma unroll
            for (int r = 0; r < 4; ++r) {
                float e = __expf(st[i][r] - FIXEDM);
                rs[r] += e;
                Ps[j & 1][(prow + r) * PS + scol + i * 16 + l15] = f2bf(e);
            }
        }
        __syncthreads();   // publishes Ps[j&1]; Vs[(j+1)&1] readers done; drains loads

        // ---- O += P V (Ps[j&1], Vs[j&1]) ----
        #pragma unroll
        for (int ks = 0; ks < 2; ++ks) {
            short8 pa[2], vf[4];
            #pragma unroll
            for (int mt = 0; mt < 2; ++mt)
                pa[mt] = *(const short8*)(&Ps[j & 1][(mt * 16 + l15) * PS + ks * 32 + quad * 8]);
            #pragma unroll
            for (int nt = 0; nt < 4; ++nt) {
                int c = w * 64 + nt * 16 + l15;
                int o16 = c * 8 + ((ks * 4 + quad) ^ (l15 & 7));
                vf[nt] = *(const short8*)(&Vs[j & 1][o16 * 8]);
            }
            #pragma unroll
            for (int mt = 0; mt < 2; ++mt)
                #pragma unroll
                for (int nt = 0; nt < 4; ++nt)
                    acc[mt][nt] = __builtin_amdgcn_mfma_f32_16x16x32_bf16(
                        pa[mt], vf[nt], acc[mt][nt], 0, 0, 0);
        }

        // ---- commit staged V chunk j+1 ----
        #pragma unroll
        for (int m = 0; m < 8; ++m)
            *(short8*)(&Vs[(j + 1) & 1][(m * 256 + tid) * 8]) = vreg[m];

        #pragma unroll
        for (int i = 0; i < 2; ++i) kcur[i] = kn[i];
    }

    // ---- l: reduce over 16 s-cols, publish per (s-half, row) ----
    #pragma unroll
    for (int mask = 1; mask < 16; mask <<= 1)
        #pragma unroll
        for (int r = 0; r < 4; ++r)
            rs[r] += __shfl_xor(rs[r], mask, 64);
    if (l15 == 0) {
        #pragma unroll
        for (int r = 0; r < 4; ++r)
            lsum[sh_w][mt_w * 16 + quad * 4 + r] = rs[r];
    }
    __syncthreads();

    // ---- epilogue: out = x + gamma * O / l ----
    const float gam = gamma_p[0];
    const float* xb = x + (size_t)b * CC * TT;
    float* ob = out + (size_t)b * CC * TT;

    #pragma unroll
    for (int mt = 0; mt < 2; ++mt) {
        f32x4 l0 = *(const f32x4*)(&lsum[0][mt * 16 + quad * 4]);
        f32x4 l1 = *(const f32x4*)(&lsum[1][mt * 16 + quad * 4]);
        float li[4];
        #pragma unroll
        for (int r = 0; r < 4; ++r) li[r] = 1.0f / (l0[r] + l1[r]);
        #pragma unroll
        for (int nt = 0; nt < 4; ++nt) {
            int c = w * 64 + nt * 16 + l15;
            size_t gidx = (size_t)c * TT + t0 + mt * 16 + quad * 4;
            float4 xv = *(const float4*)(xb + gidx);
            float4 ov;
            ov.x = xv.x + gam * acc[mt][nt][0] * li[0];
            ov.y = xv.y + gam * acc[mt][nt][1] * li[1];
            ov.z = xv.z + gam * acc[mt][nt][2] * li[2];
            ov.w = xv.w + gam * acc[mt][nt][3] * li[3];
            *(float4*)(ob + gidx) = ov;
        }
    }
}

// ---------------------------------------------------------------------------
extern "C" void kernel_launch(void* const* d_in, const int* in_sizes, int n_in,
                              void* d_out, int out_size, void* d_ws, size_t ws_size,
                              hipStream_t stream)
{
    const float* x     = (const float*)d_in[0];
    const float* Wq    = (const float*)d_in[1];
    const float* bq    = (const float*)d_in[2];
    const float* Wk    = (const float*)d_in[3];
    const float* bk    = (const float*)d_in[4];
    const float* Wv    = (const float*)d_in[5];
    const float* bv    = (const float*)d_in[6];
    const float* gamma = (const float*)d_in[7];
    float* out = (float*)d_out;

    unsigned short* qws = (unsigned short*)d_ws;            // [B][T][R] bf16
    unsigned short* kws = qws + (size_t)BB * TT * RR;       // [B][T][R] bf16
    unsigned short* vws = kws + (size_t)BB * TT * RR;       // [B][C][T] bf16
    unsigned short* wqb = vws + (size_t)BB * CC * TT;       // [R][C] bf16
    unsigned short* wkb = wqb + (size_t)RR * CC;
    unsigned short* wvb = wkb + (size_t)RR * CC;            // [C][C] bf16

    wcast_kernel<<<80, 256, 0, stream>>>(Wq, Wk, Wv, wqb, wkb, wvb);

    dim3 pgrid(TT / PT, BB);
    proj_kernel<<<pgrid, 256, 0, stream>>>(x, wqb, bq, wkb, bk, wvb, bv, qws, kws, vws);

    dim3 agrid(BB, TT / ATILE);
    attn_kernel<<<agrid, 256, 0, stream>>>(x, qws, kws, vws, gamma, out);
}

// Round 8
// 129.442 us; speedup vs baseline: 1.3048x; 1.0639x over previous
//
#include <hip/hip_runtime.h>
#include <hip/hip_bf16.h>
#include <math.h>

// Problem constants
constexpr int BB = 8;
constexpr int CC = 256;
constexpr int TT = 2048;
constexpr int RR = 32;      // reduced dim

// attn
constexpr int ATILE = 64;   // t rows per attn block (8 waves)
constexpr int PS = 72;      // Ps stride (bf16), 144B rows (bank-uniform b128 reads)
// Vs: swizzled, stride 64 bf16 = 128B rows. 16B slot for (c, sgroup=s/8) is
// sgroup ^ (c&7). Staging writes linear (conflict-free); b128 frag reads hit
// the 8-dword/bank wave64 minimum.

// proj
constexpr int PT  = 32;     // t-tile
constexpr int XS32 = 33;    // fp32 [c][t] stride
constexpr int XSB  = 264;   // bf16 [t][c] stride (528B rows)

constexpr float FIXEDM = 24.0f;  // fixed softmax shift; scores ~N(0,5.7)

typedef short short8 __attribute__((ext_vector_type(8)));
typedef float f32x4 __attribute__((ext_vector_type(4)));
typedef unsigned short us4 __attribute__((ext_vector_type(4)));

static __device__ __forceinline__ unsigned short f2bf(float f) {
    __hip_bfloat16 h = __float2bfloat16(f);
    return *reinterpret_cast<unsigned short*>(&h);
}

// ---------------------------------------------------------------------------
// One-shot W cast fp32 -> bf16.
// ---------------------------------------------------------------------------
__global__ __launch_bounds__(256) void wcast_kernel(
    const float* __restrict__ Wq, const float* __restrict__ Wk,
    const float* __restrict__ Wv,
    unsigned short* __restrict__ wqb, unsigned short* __restrict__ wkb,
    unsigned short* __restrict__ wvb)
{
    int g = blockIdx.x * 256 + threadIdx.x;   // float4 index, 20480 total
    const float* src; unsigned short* dst; int i4;
    if (g < 2048)       { src = Wq; dst = wqb; i4 = g; }
    else if (g < 4096)  { src = Wk; dst = wkb; i4 = g - 2048; }
    else                { src = Wv; dst = wvb; i4 = g - 4096; }
    float4 v = *(const float4*)(src + i4 * 4);
    us4 p;
    p[0] = f2bf(v.x); p[1] = f2bf(v.y); p[2] = f2bf(v.z); p[3] = f2bf(v.w);
    *(us4*)(dst + i4 * 4) = p;
}

// ---------------------------------------------------------------------------
// MFMA projection (unchanged from R7: ~18 us). 512 blocks.
// ---------------------------------------------------------------------------
__global__ __launch_bounds__(256, 2) void proj_kernel(
    const float* __restrict__ x,
    const unsigned short* __restrict__ wqb, const float* __restrict__ bq,
    const unsigned short* __restrict__ wkb, const float* __restrict__ bk,
    const unsigned short* __restrict__ wvb, const float* __restrict__ bv,
    unsigned short* __restrict__ qws, unsigned short* __restrict__ kws,
    unsigned short* __restrict__ vws)
{
    __shared__ float xs32[CC * XS32];            // [c][t] 33.8 KB
    __shared__ unsigned short xsb[PT * XSB];     // [t][c] 16.9 KB

    const int tid = threadIdx.x;
    const int t0  = blockIdx.x * PT;
    const int b   = blockIdx.y;
    const float* xb = x + (size_t)b * CC * TT;

    #pragma unroll
    for (int m = 0; m < 8; ++m) {
        int lin = m * 256 + tid;     // float4 index
        int c   = lin >> 3;
        int t4  = lin & 7;
        float4 v = *(const float4*)(xb + (size_t)c * TT + t0 + t4 * 4);
        float* d = &xs32[c * XS32 + t4 * 4];
        d[0] = v.x; d[1] = v.y; d[2] = v.z; d[3] = v.w;
    }
    __syncthreads();
    {
        int c = tid;
        #pragma unroll
        for (int t = 0; t < PT; ++t)
            xsb[t * XSB + c] = f2bf(xs32[c * XS32 + t]);
    }
    __syncthreads();

    const int lane = tid & 63;
    const int w    = __builtin_amdgcn_readfirstlane(tid >> 6);
    const int l15  = lane & 15;
    const int quad = lane >> 4;

    const unsigned short* Wt[5]; const float* bt[5]; int rl[5]; int seg[5];
    #pragma unroll
    for (int i = 0; i < 5; ++i) {
        int mt = w * 5 + i;
        if (mt < 2)      { Wt[i] = wqb; bt[i] = bq; rl[i] = mt * 16;       seg[i] = 0; }
        else if (mt < 4) { Wt[i] = wkb; bt[i] = bk; rl[i] = (mt - 2) * 16; seg[i] = 1; }
        else             { Wt[i] = wvb; bt[i] = bv; rl[i] = (mt - 4) * 16; seg[i] = 2; }
    }

    f32x4 acc[5][2];
    #pragma unroll
    for (int i = 0; i < 5; ++i) {
        float4 bb = *(const float4*)(bt[i] + rl[i] + quad * 4);
        #pragma unroll
        for (int nt = 0; nt < 2; ++nt)
            acc[i][nt] = (f32x4){bb.x, bb.y, bb.z, bb.w};
    }

    #pragma unroll
    for (int ks = 0; ks < 8; ++ks) {
        short8 bfr[2];
        #pragma unroll
        for (int nt = 0; nt < 2; ++nt)
            bfr[nt] = *(const short8*)(&xsb[(nt * 16 + l15) * XSB + ks * 32 + quad * 8]);
        #pragma unroll
        for (int i = 0; i < 5; ++i) {
            short8 af = *(const short8*)(Wt[i] + (size_t)(rl[i] + l15) * CC + ks * 32 + quad * 8);
            #pragma unroll
            for (int nt = 0; nt < 2; ++nt)
                acc[i][nt] = __builtin_amdgcn_mfma_f32_16x16x32_bf16(
                    af, bfr[nt], acc[i][nt], 0, 0, 0);
        }
    }

    #pragma unroll
    for (int i = 0; i < 5; ++i) {
        if (seg[i] < 2) {
            unsigned short* outt = (seg[i] == 0 ? qws : kws) + (size_t)b * TT * RR;
            #pragma unroll
            for (int nt = 0; nt < 2; ++nt) {
                int t = t0 + nt * 16 + l15;
                us4 pk;
                pk[0] = f2bf(acc[i][nt][0]); pk[1] = f2bf(acc[i][nt][1]);
                pk[2] = f2bf(acc[i][nt][2]); pk[3] = f2bf(acc[i][nt][3]);
                *(us4*)(outt + (size_t)t * RR + rl[i] + quad * 4) = pk;
            }
        } else {
            unsigned short* vt = vws + (size_t)b * CC * TT;
            #pragma unroll
            for (int nt = 0; nt < 2; ++nt)
                #pragma unroll
                for (int r = 0; r < 4; ++r)
                    vt[(size_t)(rl[i] + quad * 4 + r) * TT + t0 + nt * 16 + l15] =
                        f2bf(acc[i][nt][r]);
        }
    }
}

// ---------------------------------------------------------------------------
// MFMA flash attention v8: ATILE=64, 8 waves (512 thr), grid 256 = 1 block/CU.
// Halves V L2 traffic AND barriers per unit work vs v7. Single barrier per
// 64-s chunk; dbuf swizzled Vs (2x32 KB) + dbuf Ps (2x9.2 KB); manual register
// staging (loads at iter top, ds_write commit post-barrier -- safe because
// barrier j guarantees all waves finished PV(j-1), the last reader of buffer
// (j+1)&1).
// Wave roles: S tiles (mt_s=w&3, s-half=w>>2); PV rect 32t x 64c
// (mth=w>>2, cq=w&3) -- minimal total fragment traffic tiling.
// ---------------------------------------------------------------------------
__global__ __launch_bounds__(512, 2) void attn_kernel(
    const float* __restrict__ x,
    const unsigned short* __restrict__ qws, const unsigned short* __restrict__ kws,
    const unsigned short* __restrict__ vws, const float* __restrict__ gamma_p,
    float* __restrict__ out)
{
    __shared__ unsigned short Vs[2][CC * 64];      // swizzled, 64 KB
    __shared__ unsigned short Ps[2][ATILE * PS];   // 18.4 KB
    __shared__ float lsum[2][ATILE];

    const int tid  = threadIdx.x;                  // 0..511
    const int b    = blockIdx.x;                   // linear%8 = b -> XCD-local L2
    const int t0   = blockIdx.y * ATILE;
    const int lane = tid & 63;
    const int w    = __builtin_amdgcn_readfirstlane(tid >> 6);   // 0..7
    const int mt_s = w & 3;                        // S row-tile
    const int sh_w = w >> 2;                       // S s-half
    const int mth  = w >> 2;                       // PV row-half (32 t)
    const int cq   = w & 3;                        // PV c-quarter (64 c)
    const int l15  = lane & 15;
    const int quad = lane >> 4;

    const unsigned short* qb = qws + (size_t)b * TT * RR;
    const unsigned short* kb = kws + (size_t)b * TT * RR;
    const unsigned short* vb = vws + (size_t)b * CC * TT;

    // Q A-frag for the wave's S rows
    short8 qfrag = *(const short8*)(qb + (size_t)(t0 + mt_s * 16 + l15) * RR + quad * 8);

    // V staging identity: thread covers 16B slots o16 = m*512 + tid (m=0..3);
    // c = m*64 + (tid>>3), slot = tid&7, source s-group = slot ^ (c&7).
    const int crow = tid >> 3;                     // 0..63
    const int sg   = (tid & 7) ^ (crow & 7);
    const unsigned short* vstg = vb + (size_t)crow * TT + sg * 8;

    // K B-frag base: row = s0 + sh_w*32 + i*16 + l15
    const unsigned short* kbase = kb + (size_t)(sh_w * 32 + l15) * RR + quad * 8;

    float rs[4];
    #pragma unroll
    for (int r = 0; r < 4; ++r) rs[r] = 0.0f;

    f32x4 acc[2][4];
    #pragma unroll
    for (int mt = 0; mt < 2; ++mt)
        #pragma unroll
        for (int nt = 0; nt < 4; ++nt)
            acc[mt][nt] = (f32x4){0.f, 0.f, 0.f, 0.f};

    const f32x4 zz = (f32x4){0.f, 0.f, 0.f, 0.f};

    short8 vreg[4], kcur[2], kn[2];

    // ---- prologue: chunk 0 -> regs -> Vs[0]; K(0) -> kcur ----
    #pragma unroll
    for (int m = 0; m < 4; ++m)
        vreg[m] = *(const short8*)(vstg + (size_t)(m * 64) * TT);
    #pragma unroll
    for (int i = 0; i < 2; ++i)
        kcur[i] = *(const short8*)(kbase + (size_t)(i * 16) * RR);
    #pragma unroll
    for (int m = 0; m < 4; ++m)
        *(short8*)(&Vs[0][(m * 512 + tid) * 8]) = vreg[m];

    #pragma unroll 2
    for (int j = 0; j < 32; ++j) {
        // ---- issue next chunk's staging loads (regs; wrap at 31 harmless) ----
        const int s1 = ((j + 1) & 31) * 64;
        #pragma unroll
        for (int m = 0; m < 4; ++m)
            vreg[m] = *(const short8*)(vstg + (size_t)(m * 64) * TT + s1);
        #pragma unroll
        for (int i = 0; i < 2; ++i)
            kn[i] = *(const short8*)(kbase + (size_t)(s1 + i * 16) * RR);

        // ---- S = Q K^T (2 tiles, K from regs) ----
        f32x4 st[2];
        #pragma unroll
        for (int i = 0; i < 2; ++i)
            st[i] = __builtin_amdgcn_mfma_f32_16x16x32_bf16(qfrag, kcur[i], zz, 0, 0, 0);

        // ---- P = exp(S-M), row-sum partials, Ps[j&1] ----
        const int prow = mt_s * 16 + quad * 4;
        const int scol = sh_w * 32;
        #pragma unroll
        for (int i = 0; i < 2; ++i) {
            #pragma unroll
            for (int r = 0; r < 4; ++r) {
                float e = __expf(st[i][r] - FIXEDM);
                rs[r] += e;
                Ps[j & 1][(prow + r) * PS + scol + i * 16 + l15] = f2bf(e);
            }
        }
        __syncthreads();   // publishes Ps[j&1]; all waves past PV(j-1)

        // ---- O += P V  (Ps[j&1], Vs[j&1]) ----
        #pragma unroll
        for (int ks = 0; ks < 2; ++ks) {
            short8 pa[2], vf[4];
            #pragma unroll
            for (int mt = 0; mt < 2; ++mt)
                pa[mt] = *(const short8*)(&Ps[j & 1][(mth * 32 + mt * 16 + l15) * PS + ks * 32 + quad * 8]);
            #pragma unroll
            for (int nt = 0; nt < 4; ++nt) {
                int c = cq * 64 + nt * 16 + l15;
                int o16 = c * 8 + ((ks * 4 + quad) ^ (l15 & 7));
                vf[nt] = *(const short8*)(&Vs[j & 1][o16 * 8]);
            }
            #pragma unroll
            for (int mt = 0; mt < 2; ++mt)
                #pragma unroll
                for (int nt = 0; nt < 4; ++nt)
                    acc[mt][nt] = __builtin_amdgcn_mfma_f32_16x16x32_bf16(
                        pa[mt], vf[nt], acc[mt][nt], 0, 0, 0);
        }

        // ---- commit staged V chunk j+1 into Vs[(j+1)&1] (post-barrier: safe) ----
        #pragma unroll
        for (int m = 0; m < 4; ++m)
            *(short8*)(&Vs[(j + 1) & 1][(m * 512 + tid) * 8]) = vreg[m];

        #pragma unroll
        for (int i = 0; i < 2; ++i) kcur[i] = kn[i];
    }

    // ---- l: reduce over 16 s-cols (lane groups), publish per (s-half, row) ----
    #pragma unroll
    for (int mask = 1; mask < 16; mask <<= 1)
        #pragma unroll
        for (int r = 0; r < 4; ++r)
            rs[r] += __shfl_xor(rs[r], mask, 64);
    if (l15 == 0) {
        #pragma unroll
        for (int r = 0; r < 4; ++r)
            lsum[sh_w][mt_s * 16 + quad * 4 + r] = rs[r];
    }
    __syncthreads();

    // ---- epilogue: out = x + gamma * O / l ----
    const float gam = gamma_p[0];
    const float* xb = x + (size_t)b * CC * TT;
    float* ob = out + (size_t)b * CC * TT;

    #pragma unroll
    for (int mt = 0; mt < 2; ++mt) {
        int tbase = mth * 32 + mt * 16 + quad * 4;
        f32x4 l0 = *(const f32x4*)(&lsum[0][tbase]);
        f32x4 l1 = *(const f32x4*)(&lsum[1][tbase]);
        float li[4];
        #pragma unroll
        for (int r = 0; r < 4; ++r) li[r] = 1.0f / (l0[r] + l1[r]);
        #pragma unroll
        for (int nt = 0; nt < 4; ++nt) {
            int c = cq * 64 + nt * 16 + l15;
            size_t gidx = (size_t)c * TT + t0 + tbase;
            float4 xv = *(const float4*)(xb + gidx);
            float4 ov;
            ov.x = xv.x + gam * acc[mt][nt][0] * li[0];
            ov.y = xv.y + gam * acc[mt][nt][1] * li[1];
            ov.z = xv.z + gam * acc[mt][nt][2] * li[2];
            ov.w = xv.w + gam * acc[mt][nt][3] * li[3];
            *(float4*)(ob + gidx) = ov;
        }
    }
}

// ---------------------------------------------------------------------------
extern "C" void kernel_launch(void* const* d_in, const int* in_sizes, int n_in,
                              void* d_out, int out_size, void* d_ws, size_t ws_size,
                              hipStream_t stream)
{
    const float* x     = (const float*)d_in[0];
    const float* Wq    = (const float*)d_in[1];
    const float* bq    = (const float*)d_in[2];
    const float* Wk    = (const float*)d_in[3];
    const float* bk    = (const float*)d_in[4];
    const float* Wv    = (const float*)d_in[5];
    const float* bv    = (const float*)d_in[6];
    const float* gamma = (const float*)d_in[7];
    float* out = (float*)d_out;

    unsigned short* qws = (unsigned short*)d_ws;            // [B][T][R] bf16
    unsigned short* kws = qws + (size_t)BB * TT * RR;       // [B][T][R] bf16
    unsigned short* vws = kws + (size_t)BB * TT * RR;       // [B][C][T] bf16
    unsigned short* wqb = vws + (size_t)BB * CC * TT;       // [R][C] bf16
    unsigned short* wkb = wqb + (size_t)RR * CC;
    unsigned short* wvb = wkb + (size_t)RR * CC;            // [C][C] bf16

    wcast_kernel<<<80, 256, 0, stream>>>(Wq, Wk, Wv, wqb, wkb, wvb);

    dim3 pgrid(TT / PT, BB);
    proj_kernel<<<pgrid, 256, 0, stream>>>(x, wqb, bq, wkb, bk, wvb, bv, qws, kws, vws);

    dim3 agrid(BB, TT / ATILE);
    attn_kernel<<<agrid, 512, 0, stream>>>(x, qws, kws, vws, gamma, out);
}